// Round 1
// baseline (679.225 us; speedup 1.0000x reference)
//
#include <hip/hip_runtime.h>

#define N_NODES 2000
#define BATCH   32
#define DIM     64      // DIM_IN == DIM_OUT
#define EMB     16
#define KI      192     // CHEB_K * DIM_IN

// ---------------------------------------------------------------------------
// Kernel 1: s = softmax(relu(nv1 @ nv2), axis=1)   [N,N]
// One block per row. Row of 2000 logits staged in LDS, two-pass softmax.
// ---------------------------------------------------------------------------
__global__ __launch_bounds__(256) void adj_softmax_kernel(
    const float* __restrict__ nv1, const float* __restrict__ nv2,
    float* __restrict__ s)
{
    const int row = blockIdx.x;
    const int tid = threadIdx.x;
    __shared__ float sa[EMB];
    __shared__ float z[N_NODES];
    __shared__ float wred[4];
    __shared__ float bcast;
    if (tid < EMB) sa[tid] = nv1[row * EMB + tid];
    __syncthreads();

    float lmax = 0.0f;  // relu output >= 0
    for (int j = tid; j < N_NODES; j += 256) {
        float acc = 0.0f;
#pragma unroll
        for (int d = 0; d < EMB; ++d) acc += sa[d] * nv2[d * N_NODES + j];
        acc = fmaxf(acc, 0.0f);
        z[j] = acc;
        lmax = fmaxf(lmax, acc);
    }
#pragma unroll
    for (int off = 32; off > 0; off >>= 1)
        lmax = fmaxf(lmax, __shfl_down(lmax, off, 64));
    if ((tid & 63) == 0) wred[tid >> 6] = lmax;
    __syncthreads();
    if (tid == 0) bcast = fmaxf(fmaxf(wred[0], wred[1]), fmaxf(wred[2], wred[3]));
    __syncthreads();
    const float rmax = bcast;

    float lsum = 0.0f;
    for (int j = tid; j < N_NODES; j += 256) {
        float e = __expf(z[j] - rmax);
        z[j] = e;
        lsum += e;
    }
#pragma unroll
    for (int off = 32; off > 0; off >>= 1)
        lsum += __shfl_down(lsum, off, 64);
    if ((tid & 63) == 0) wred[tid >> 6] = lsum;
    __syncthreads();
    if (tid == 0) bcast = wred[0] + wred[1] + wred[2] + wred[3];
    __syncthreads();
    const float inv = 1.0f / bcast;
    for (int j = tid; j < N_NODES; j += 256)
        s[(size_t)row * N_NODES + j] = z[j] * inv;
}

// ---------------------------------------------------------------------------
// Kernel 2: Y[b,n,c] = sum_m S[n,m] * X[b,m,c]
// Tiled fp32 GEMM: 64 (n) x 64 (c, exactly one batch b) x 16 (m) tiles,
// 256 threads, 4x4 micro-tile per thread.
// ---------------------------------------------------------------------------
__global__ __launch_bounds__(256) void spmm_kernel(
    const float* __restrict__ S, const float* __restrict__ X,
    float* __restrict__ Y)
{
    const int b  = blockIdx.y;
    const int n0 = blockIdx.x * 64;
    const int tid = threadIdx.x;
    const int tx = tid & 15;   // c quad
    const int ty = tid >> 4;   // n quad

    __shared__ float sS[16][65];  // [k][n], +1 pad breaks transpose-write conflicts
    __shared__ float sX[16][64];  // [k][c], contiguous rows -> float4 reads

    float acc[4][4] = {};
    const float* Xb = X + (size_t)b * (N_NODES * DIM);

    for (int k0 = 0; k0 < N_NODES; k0 += 16) {
        // stage S tile (rows n0..n0+63, cols k0..k0+15), transposed to [k][n]
#pragma unroll
        for (int q = 0; q < 4; ++q) {
            int l  = q * 256 + tid;
            int i  = l >> 4;    // n offset 0..63
            int kk = l & 15;    // k offset 0..15
            int n  = n0 + i;
            sS[kk][i] = (n < N_NODES) ? S[(size_t)n * N_NODES + k0 + kk] : 0.0f;
        }
        // stage X tile (rows k0..k0+15, cols 0..63) — contiguous, coalesced
#pragma unroll
        for (int q = 0; q < 4; ++q) {
            int l = q * 256 + tid;
            int r = l >> 6;     // k offset 0..15
            int c = l & 63;
            sX[r][c] = Xb[(size_t)(k0 + r) * DIM + c];
        }
        __syncthreads();

#pragma unroll
        for (int k = 0; k < 16; ++k) {
            const float4 xv = *(const float4*)&sX[k][tx * 4];
            const float a0 = sS[k][ty * 4 + 0];
            const float a1 = sS[k][ty * 4 + 1];
            const float a2 = sS[k][ty * 4 + 2];
            const float a3 = sS[k][ty * 4 + 3];
            acc[0][0] += a0 * xv.x; acc[0][1] += a0 * xv.y; acc[0][2] += a0 * xv.z; acc[0][3] += a0 * xv.w;
            acc[1][0] += a1 * xv.x; acc[1][1] += a1 * xv.y; acc[1][2] += a1 * xv.z; acc[1][3] += a1 * xv.w;
            acc[2][0] += a2 * xv.x; acc[2][1] += a2 * xv.y; acc[2][2] += a2 * xv.z; acc[2][3] += a2 * xv.w;
            acc[3][0] += a3 * xv.x; acc[3][1] += a3 * xv.y; acc[3][2] += a3 * xv.z; acc[3][3] += a3 * xv.w;
        }
        __syncthreads();
    }

#pragma unroll
    for (int a = 0; a < 4; ++a) {
        int n = n0 + ty * 4 + a;
        if (n < N_NODES) {
            float4 v = make_float4(acc[a][0], acc[a][1], acc[a][2], acc[a][3]);
            *(float4*)&Y[((size_t)b * N_NODES + n) * DIM + tx * 4] = v;
        }
    }
}

// ---------------------------------------------------------------------------
// Kernel 3: per-node combine.
// W_n[k,i,o] = sum_d emb[n,d]*wp[d,k,i,o] built in LDS (48 KB), then
// out[b,n,o] = sum_{k,i} xg[b,n,k,i]*W_n[k,i,o] + bias[n,o],
// with xg = { x, y1, 2*y2 - x }.
// ---------------------------------------------------------------------------
__global__ __launch_bounds__(256) void combine_kernel(
    const float* __restrict__ x,  const float* __restrict__ y1,
    const float* __restrict__ y2, const float* __restrict__ emb,
    const float* __restrict__ wp, const float* __restrict__ bias_pool,
    float* __restrict__ out)
{
    const int n = blockIdx.x;
    const int tid = threadIdx.x;
    __shared__ float s_emb[EMB];
    __shared__ float sW[KI * DIM];       // [j = k*64+i][o]  48 KiB
    __shared__ float sA[BATCH * KI];     // [b][j]           24 KiB
    __shared__ float sbias[DIM];

    if (tid < EMB) s_emb[tid] = emb[n * EMB + tid];
    __syncthreads();

    // node-conditioned weights (wp streamed coalesced, L2-resident)
    for (int idx = tid; idx < KI * DIM; idx += 256) {
        float acc = 0.0f;
#pragma unroll
        for (int d = 0; d < EMB; ++d) acc += s_emb[d] * wp[d * (KI * DIM) + idx];
        sW[idx] = acc;
    }
    if (tid < DIM) {
        float acc = 0.0f;
#pragma unroll
        for (int d = 0; d < EMB; ++d) acc += s_emb[d] * bias_pool[d * DIM + tid];
        sbias[tid] = acc;
    }
    // x_g for this node: [b][0..63]=x, [64..127]=y1, [128..191]=2*y2-x
    for (int t = tid; t < BATCH * DIM; t += 256) {
        int b = t >> 6, i = t & 63;
        size_t g = ((size_t)b * N_NODES + n) * DIM + i;
        float xv = x[g], v1 = y1[g], v2 = y2[g];
        sA[b * KI + i]       = xv;
        sA[b * KI + 64 + i]  = v1;
        sA[b * KI + 128 + i] = 2.0f * v2 - xv;
    }
    __syncthreads();

    const int o  = tid & 63;   // output channel (one wave = one batch slice)
    const int bq = tid >> 6;   // wave id -> handles 8 batches
    float acc[8];
#pragma unroll
    for (int bb = 0; bb < 8; ++bb) acc[bb] = sbias[o];
    for (int j = 0; j < KI; ++j) {
        const float w = sW[j * DIM + o];   // 2-way bank alias: free
#pragma unroll
        for (int bb = 0; bb < 8; ++bb)
            acc[bb] += sA[(bq * 8 + bb) * KI + j] * w;  // wave-broadcast
    }
#pragma unroll
    for (int bb = 0; bb < 8; ++bb)
        out[(((size_t)(bq * 8 + bb)) * N_NODES + n) * DIM + o] = acc[bb];
}

// ---------------------------------------------------------------------------
extern "C" void kernel_launch(void* const* d_in, const int* in_sizes, int n_in,
                              void* d_out, int out_size, void* d_ws, size_t ws_size,
                              hipStream_t stream) {
    const float* x   = (const float*)d_in[0];  // [32,2000,64]
    const float* emb = (const float*)d_in[1];  // [2000,16]
    const float* nv1 = (const float*)d_in[2];  // [2000,16]
    const float* nv2 = (const float*)d_in[3];  // [16,2000]
    const float* wp  = (const float*)d_in[4];  // [16,3,64,64]
    const float* bp  = (const float*)d_in[5];  // [16,64]
    float* out = (float*)d_out;                // [32,2000,64]

    float* ws = (float*)d_ws;
    float* s  = ws;                            // 4,000,000 floats (16 MB)
    float* y1 = ws + 4000000;                  // 4,096,000 floats
    float* y2 = y1 + 4096000;                  // 4,096,000 floats

    adj_softmax_kernel<<<N_NODES, 256, 0, stream>>>(nv1, nv2, s);
    spmm_kernel<<<dim3(32, 32), 256, 0, stream>>>(s, x,  y1);  // y1 = s @ x
    spmm_kernel<<<dim3(32, 32), 256, 0, stream>>>(s, y1, y2);  // y2 = s @ y1
    combine_kernel<<<N_NODES, 256, 0, stream>>>(x, y1, y2, emb, wp, bp, out);
}

// Round 2
// 288.527 us; speedup vs baseline: 2.3541x; 2.3541x over previous
//
#include <hip/hip_runtime.h>

#define N_NODES 2000
#define BATCH   32
#define DIM     64      // DIM_IN == DIM_OUT
#define EMB     16
#define KI      192     // CHEB_K * DIM_IN

typedef __bf16 bf16;
typedef __attribute__((ext_vector_type(8))) __bf16 bf16x8;
typedef __attribute__((ext_vector_type(4))) float  f32x4;

struct alignas(8) bf16x4pk { bf16 v[4]; };

// ---------------------------------------------------------------------------
// Kernel 1: s = softmax(relu(nv1 @ nv2), axis=1)   [N,N], output bf16
// One block per row. Row of 2000 logits staged in LDS, two-pass softmax.
// ---------------------------------------------------------------------------
__global__ __launch_bounds__(256) void adj_softmax_kernel(
    const float* __restrict__ nv1, const float* __restrict__ nv2,
    bf16* __restrict__ s)
{
    const int row = blockIdx.x;
    const int tid = threadIdx.x;
    __shared__ float sa[EMB];
    __shared__ float z[N_NODES];
    __shared__ float wred[4];
    __shared__ float bcast;
    if (tid < EMB) sa[tid] = nv1[row * EMB + tid];
    __syncthreads();

    float lmax = 0.0f;  // relu output >= 0
    for (int j = tid; j < N_NODES; j += 256) {
        float acc = 0.0f;
#pragma unroll
        for (int d = 0; d < EMB; ++d) acc += sa[d] * nv2[d * N_NODES + j];
        acc = fmaxf(acc, 0.0f);
        z[j] = acc;
        lmax = fmaxf(lmax, acc);
    }
#pragma unroll
    for (int off = 32; off > 0; off >>= 1)
        lmax = fmaxf(lmax, __shfl_down(lmax, off, 64));
    if ((tid & 63) == 0) wred[tid >> 6] = lmax;
    __syncthreads();
    if (tid == 0) bcast = fmaxf(fmaxf(wred[0], wred[1]), fmaxf(wred[2], wred[3]));
    __syncthreads();
    const float rmax = bcast;

    float lsum = 0.0f;
    for (int j = tid; j < N_NODES; j += 256) {
        float e = __expf(z[j] - rmax);
        z[j] = e;
        lsum += e;
    }
#pragma unroll
    for (int off = 32; off > 0; off >>= 1)
        lsum += __shfl_down(lsum, off, 64);
    if ((tid & 63) == 0) wred[tid >> 6] = lsum;
    __syncthreads();
    if (tid == 0) bcast = wred[0] + wred[1] + wred[2] + wred[3];
    __syncthreads();
    const float inv = 1.0f / bcast;
    for (int j = tid; j < N_NODES; j += 256)
        s[(size_t)row * N_NODES + j] = (bf16)(z[j] * inv);
}

// ---------------------------------------------------------------------------
// Kernel 2: transpose+cast x [b][m][c] fp32 -> xT [b][c][m] bf16
// (B-operand for MFMA wants k(=m)-contiguous per column c)
// ---------------------------------------------------------------------------
__global__ __launch_bounds__(256) void transpose_cast_x(
    const float* __restrict__ X, bf16* __restrict__ Xt)
{
    const int b  = blockIdx.y;
    const int m0 = blockIdx.x * 64;
    const int tid = threadIdx.x;
    __shared__ bf16 T[64][72];   // [c][m], padded
#pragma unroll
    for (int i = 0; i < 4; ++i) {
        int idx = i * 256 + tid;       // 0..1023
        int r  = idx >> 4;             // m row offset 0..63
        int c4 = (idx & 15) * 4;
        float4 v = make_float4(0.f, 0.f, 0.f, 0.f);
        if (m0 + r < N_NODES)
            v = *(const float4*)&X[((size_t)b * N_NODES + m0 + r) * DIM + c4];
        T[c4 + 0][r] = (bf16)v.x;
        T[c4 + 1][r] = (bf16)v.y;
        T[c4 + 2][r] = (bf16)v.z;
        T[c4 + 3][r] = (bf16)v.w;
    }
    __syncthreads();
#pragma unroll
    for (int i = 0; i < 4; ++i) {
        int idx = i * 256 + tid;
        int c  = idx >> 4;
        int mc = idx & 15;
        if (m0 + mc * 4 + 4 <= N_NODES) {
            bf16x4pk pk;
            pk.v[0] = T[c][mc * 4 + 0];
            pk.v[1] = T[c][mc * 4 + 1];
            pk.v[2] = T[c][mc * 4 + 2];
            pk.v[3] = T[c][mc * 4 + 3];
            *(bf16x4pk*)&Xt[(size_t)(b * DIM + c) * N_NODES + m0 + mc * 4] = pk;
        }
    }
}

// ---------------------------------------------------------------------------
// Kernel 3: Y[b,n,c] = sum_m S[n,m] * X[b,m,c]  via mfma_f32_16x16x32_bf16
// Block: 64 n-rows x 64 c-cols (one batch). 4 waves in 2x2, each wave 32x32
// (2x2 tiles of 16x16). K-step 32. LDS tiles padded to stride 40 (2-way
// bank alias only = free). Writes fp32 Y [b][n][c]; optionally bf16
// transposed Yt [b][c][n] to feed the next spmm's B operand.
// ---------------------------------------------------------------------------
__global__ __launch_bounds__(256) void spmm_mfma(
    const bf16* __restrict__ S, const bf16* __restrict__ Bt,
    float* __restrict__ Y, bf16* __restrict__ Yt, int write_yt)
{
    const int b   = blockIdx.x;          // batch fastest -> S tile shared in L2
    const int n0  = blockIdx.y * 64;
    const int tid = threadIdx.x;
    const int lane = tid & 63;
    const int wave = tid >> 6;
    const int wm = wave >> 1, wn = wave & 1;
    const int l15 = lane & 15, quad = lane >> 4;

    __shared__ bf16 As[64][40];   // [n][k] padded
    __shared__ bf16 Bs[64][40];   // [c][k] padded

    f32x4 acc[2][2] = {};

    const int srow = tid >> 2;          // 0..63
    const int soff = (tid & 3) * 8;     // 0,8,16,24
    const bf16* Btb = Bt + (size_t)b * DIM * N_NODES;

    for (int k0 = 0; k0 < N_NODES; k0 += 32) {
        const int an = n0 + srow;
        const int kk = k0 + soff;
        bf16x8 av = {}, bv = {};
        const bool kok = (kk + 8 <= N_NODES);   // N_NODES % 8 == 0: all-or-nothing
        if (kok && an < N_NODES)
            av = *(const bf16x8*)&S[(size_t)an * N_NODES + kk];
        if (kok)
            bv = *(const bf16x8*)&Btb[(size_t)srow * N_NODES + kk];
        __syncthreads();                 // protect LDS vs previous iter's reads
        *(bf16x8*)&As[srow][soff] = av;
        *(bf16x8*)&Bs[srow][soff] = bv;
        __syncthreads();

        bf16x8 af[2], bfr[2];
#pragma unroll
        for (int rt = 0; rt < 2; ++rt)
            af[rt] = *(const bf16x8*)&As[wm * 32 + rt * 16 + l15][quad * 8];
#pragma unroll
        for (int ct = 0; ct < 2; ++ct)
            bfr[ct] = *(const bf16x8*)&Bs[wn * 32 + ct * 16 + l15][quad * 8];
#pragma unroll
        for (int rt = 0; rt < 2; ++rt)
#pragma unroll
            for (int ct = 0; ct < 2; ++ct)
                acc[rt][ct] = __builtin_amdgcn_mfma_f32_16x16x32_bf16(
                    af[rt], bfr[ct], acc[rt][ct], 0, 0, 0);
    }

    // Epilogue. C/D layout (m89): col = lane&15, row = quad*4 + reg
#pragma unroll
    for (int rt = 0; rt < 2; ++rt) {
        const int nbase = n0 + wm * 32 + rt * 16 + quad * 4;
#pragma unroll
        for (int ct = 0; ct < 2; ++ct) {
            const int c = wn * 32 + ct * 16 + l15;
#pragma unroll
            for (int r = 0; r < 4; ++r) {
                int n = nbase + r;
                if (n < N_NODES)
                    Y[((size_t)b * N_NODES + n) * DIM + c] = acc[rt][ct][r];
            }
            if (write_yt && nbase + 4 <= N_NODES) {  // nbase%4==0, N%4==0
                bf16x4pk pk;
                pk.v[0] = (bf16)acc[rt][ct][0];
                pk.v[1] = (bf16)acc[rt][ct][1];
                pk.v[2] = (bf16)acc[rt][ct][2];
                pk.v[3] = (bf16)acc[rt][ct][3];
                *(bf16x4pk*)&Yt[(size_t)(b * DIM + c) * N_NODES + nbase] = pk;
            }
        }
    }
}

// ---------------------------------------------------------------------------
// Kernel 4: per-node combine.
// W_n[k,i,o] = sum_d emb[n,d]*wp[d,k,i,o] built in LDS (48 KB), then
// out[b,n,o] = sum_{k,i} xg[b,n,k,i]*W_n[k,i,o] + bias[n,o],
// with xg = { x, y1, 2*y2 - x }.
// ---------------------------------------------------------------------------
__global__ __launch_bounds__(256) void combine_kernel(
    const float* __restrict__ x,  const float* __restrict__ y1,
    const float* __restrict__ y2, const float* __restrict__ emb,
    const float* __restrict__ wp, const float* __restrict__ bias_pool,
    float* __restrict__ out)
{
    const int n = blockIdx.x;
    const int tid = threadIdx.x;
    __shared__ float s_emb[EMB];
    __shared__ float sW[KI * DIM];       // [j = k*64+i][o]  48 KiB
    __shared__ float sA[BATCH * KI];     // [b][j]           24 KiB
    __shared__ float sbias[DIM];

    if (tid < EMB) s_emb[tid] = emb[n * EMB + tid];
    __syncthreads();

    for (int idx = tid; idx < KI * DIM; idx += 256) {
        float acc = 0.0f;
#pragma unroll
        for (int d = 0; d < EMB; ++d) acc += s_emb[d] * wp[d * (KI * DIM) + idx];
        sW[idx] = acc;
    }
    if (tid < DIM) {
        float acc = 0.0f;
#pragma unroll
        for (int d = 0; d < EMB; ++d) acc += s_emb[d] * bias_pool[d * DIM + tid];
        sbias[tid] = acc;
    }
    for (int t = tid; t < BATCH * DIM; t += 256) {
        int b = t >> 6, i = t & 63;
        size_t g = ((size_t)b * N_NODES + n) * DIM + i;
        float xv = x[g], v1 = y1[g], v2 = y2[g];
        sA[b * KI + i]       = xv;
        sA[b * KI + 64 + i]  = v1;
        sA[b * KI + 128 + i] = 2.0f * v2 - xv;
    }
    __syncthreads();

    const int o  = tid & 63;
    const int bq = tid >> 6;
    float acc[8];
#pragma unroll
    for (int bb = 0; bb < 8; ++bb) acc[bb] = sbias[o];
    for (int j = 0; j < KI; ++j) {
        const float w = sW[j * DIM + o];
#pragma unroll
        for (int bb = 0; bb < 8; ++bb)
            acc[bb] += sA[(bq * 8 + bb) * KI + j] * w;
    }
#pragma unroll
    for (int bb = 0; bb < 8; ++bb)
        out[(((size_t)(bq * 8 + bb)) * N_NODES + n) * DIM + o] = acc[bb];
}

// ---------------------------------------------------------------------------
extern "C" void kernel_launch(void* const* d_in, const int* in_sizes, int n_in,
                              void* d_out, int out_size, void* d_ws, size_t ws_size,
                              hipStream_t stream) {
    const float* x   = (const float*)d_in[0];  // [32,2000,64]
    const float* emb = (const float*)d_in[1];  // [2000,16]
    const float* nv1 = (const float*)d_in[2];  // [2000,16]
    const float* nv2 = (const float*)d_in[3];  // [16,2000]
    const float* wp  = (const float*)d_in[4];  // [16,3,64,64]
    const float* bp  = (const float*)d_in[5];  // [16,64]
    float* out = (float*)d_out;                // [32,2000,64]

    // workspace layout (bytes):
    //   s_bf : 2000*2000*2      =  8,000,000
    //   xT   : 32*64*2000*2     =  8,192,000
    //   y1T  : 32*64*2000*2     =  8,192,000
    //   y1   : 32*2000*64*4     = 16,384,000
    //   y2   : 32*2000*64*4     = 16,384,000
    //   total                   = 57,152,000
    char* w = (char*)d_ws;
    bf16*  s_bf = (bf16*)w;               w += (size_t)N_NODES * N_NODES * 2;
    bf16*  xT   = (bf16*)w;               w += (size_t)BATCH * DIM * N_NODES * 2;
    bf16*  y1T  = (bf16*)w;               w += (size_t)BATCH * DIM * N_NODES * 2;
    float* y1   = (float*)w;              w += (size_t)BATCH * N_NODES * DIM * 4;
    float* y2   = (float*)w;

    adj_softmax_kernel<<<N_NODES, 256, 0, stream>>>(nv1, nv2, s_bf);
    transpose_cast_x<<<dim3(32, BATCH), 256, 0, stream>>>(x, xT);
    spmm_mfma<<<dim3(BATCH, 32), 256, 0, stream>>>(s_bf, xT,  y1, y1T, 1);
    spmm_mfma<<<dim3(BATCH, 32), 256, 0, stream>>>(s_bf, y1T, y2, y1T, 0);
    combine_kernel<<<N_NODES, 256, 0, stream>>>(x, y1, y2, emb, wp, bp, out);
}